// Round 2
// baseline (219.648 us; speedup 1.0000x reference)
//
#include <hip/hip_runtime.h>
#include <hip/hip_bf16.h>

// Round 17: SINGLE-buffered global_load_lds staging (m97 structure). r16's
// double-buffered 64 KB variant regressed: 2 blocks/CU occupancy + vmcnt(0)
// barrier drain = no latency hiding (the m132 trap). m97's measured 874-912 TF
// uses 32 KB single-buffer + 2 barriers/K-step and gets overlap from ~5
// resident blocks/CU (m114 implicit wave-level pipelining). Keep the src-side
// XOR swizzle (linear LDS dest, pre-swizzled global source) + swizzled reads
// (verified passing, 0 bank conflicts in r15/r16).
//
// ws layout (r10):
//   [A] qkv_b16: 3072*3840 bf16 (23.6 MB)
//   [B] hs_b   : 3072*1280 bf16 (7.9 MB)  -- reused as attn_b after gemm1
//   [C] qkvw_b : 3840*1280 bf16 (9.8 MB)  -- Qp aliases after gemm1
//   [D] projw_b: 1280*1280 bf16 (3.3 MB)
//   [E] Kp     : 9.4 MB   [F] Vp: 9.4 MB (96-wide, col80 = ones)

#define S_TOT 3072
#define DIM   1280
#define NH    16
#define HD    80
#define SEG   1024
#define TDIM  3840

typedef short v8s __attribute__((ext_vector_type(8)));
typedef float v4f __attribute__((ext_vector_type(4)));

__device__ __forceinline__ short f2bf(float v) {
  __hip_bfloat16 b = __float2bfloat16(v);
  return *reinterpret_cast<short*>(&b);
}

__device__ __forceinline__ float bf2f(short s) {
  unsigned u = ((unsigned)(unsigned short)s) << 16;
  float f;
  __builtin_memcpy(&f, &u, 4);
  return f;
}

// async global->LDS, 16B per lane, wave-uniform LDS base + lane*16 dest
__device__ __forceinline__ void gload16(const void* g, void* lds) {
  __builtin_amdgcn_global_load_lds(
      (const __attribute__((address_space(1))) char*)g,
      (__attribute__((address_space(3))) char*)lds, 16, 0, 0);
}

#define CVT_N1 (S_TOT * DIM / 4)
#define CVT_N2 (TDIM * DIM / 4)
#define CVT_N3 (DIM * DIM / 4)
__global__ __launch_bounds__(256) void cvt3(const float* __restrict__ in1,
                                            const float* __restrict__ in2,
                                            const float* __restrict__ in3,
                                            __hip_bfloat16* __restrict__ o1,
                                            __hip_bfloat16* __restrict__ o2,
                                            __hip_bfloat16* __restrict__ o3) {
  int i = blockIdx.x * 256 + threadIdx.x;
  const float* in;
  __hip_bfloat16* out;
  if (i < CVT_N1) { in = in1; out = o1; }
  else if (i < CVT_N1 + CVT_N2) { in = in2; out = o2; i -= CVT_N1; }
  else { in = in3; out = o3; i -= CVT_N1 + CVT_N2; }
  const float4 v = ((const float4*)in)[i];
  __hip_bfloat162 p0, p1;
  p0.x = __float2bfloat16(v.x); p0.y = __float2bfloat16(v.y);
  p1.x = __float2bfloat16(v.z); p1.y = __float2bfloat16(v.w);
  __hip_bfloat162* o = (__hip_bfloat162*)(out + (size_t)i * 4);
  o[0] = p0; o[1] = p1;
}

// ---------------- gemm1: 128x128, BK=64, single-buffer gload_lds --------------
// Linear LDS chunk (row, c) holds global (row, c ^ (row&7)).
__global__ __launch_bounds__(256) void gemm1_c(const __hip_bfloat16* __restrict__ A,
                                               const __hip_bfloat16* __restrict__ B,
                                               const float* __restrict__ bias,
                                               __hip_bfloat16* __restrict__ C,
                                               int M, int N, int K) {
  __shared__ __align__(16) short Abuf[8192];  // 16 KB
  __shared__ __align__(16) short Bbuf[8192];  // 16 KB  -> 32 KB total, ~5 blk/CU
  const int tid  = threadIdx.x;
  const int wave = tid >> 6;
  const int lane = tid & 63;
  const int quad = lane >> 4;
  const int l16  = lane & 15;
  const int bm = blockIdx.x * 128;   // M fastest: consecutive blocks share B
  const int bn = blockIdx.y * 128;
  const int wm = (wave >> 1) * 64;
  const int wn = (wave & 1) * 64;

  const int srow = tid >> 3;
  const int skh  = tid & 7;
  const int khs  = skh ^ (srow & 7);          // pre-swizzled source kh chunk
  const __hip_bfloat16* Ag[4];
  const __hip_bfloat16* Bg[4];
  int Lo[4];                                   // wave-uniform LDS base (shorts)
  #pragma unroll
  for (int l = 0; l < 4; ++l) {
    const int row = l * 32 + srow;
    Ag[l] = A + (size_t)(bm + row) * K + khs * 8;
    Bg[l] = B + (size_t)(bn + row) * K + khs * 8;
    Lo[l] = (l * 256 + wave * 64) * 8;         // linear chunk l*256+tid, 8 shorts
  }

  v4f acc[4][4];
  const v4f vz = {0.f, 0.f, 0.f, 0.f};
  #pragma unroll
  for (int i = 0; i < 4; ++i)
    #pragma unroll
    for (int j = 0; j < 4; ++j) acc[i][j] = vz;

  const int sw = l16 & 7;  // read-side swizzle key (row&7 == l16&7)
  const int nk = K >> 6;   // 20 slabs of 64

  for (int k = 0; k < nk; ++k) {
    const int off = k * 64;
    #pragma unroll
    for (int l = 0; l < 4; ++l) {
      gload16(Ag[l] + off, &Abuf[Lo[l]]);
      gload16(Bg[l] + off, &Bbuf[Lo[l]]);
    }
    __syncthreads();   // drains vmcnt -> LDS slab ready
    #pragma unroll
    for (int s = 0; s < 2; ++s) {
      const int khx = (s * 4 + quad) ^ sw;
      v8s af[4], bf[4];
      #pragma unroll
      for (int i = 0; i < 4; ++i) {
        af[i] = *(const v8s*)&Abuf[((wm + i * 16 + l16) * 8 + khx) * 8];
        bf[i] = *(const v8s*)&Bbuf[((wn + i * 16 + l16) * 8 + khx) * 8];
      }
      #pragma unroll
      for (int i = 0; i < 4; ++i)
        #pragma unroll
        for (int j = 0; j < 4; ++j)
          acc[i][j] = __builtin_amdgcn_mfma_f32_16x16x32_bf16(af[i], bf[j], acc[i][j], 0, 0, 0);
    }
    __syncthreads();   // all reads done before next slab overwrites
  }

  #pragma unroll
  for (int j = 0; j < 4; ++j) {
    const int col = bn + wn + j * 16 + l16;
    const float bj = bias[col];
    #pragma unroll
    for (int i = 0; i < 4; ++i) {
      const int row0 = bm + wm + i * 16 + quad * 4;
      #pragma unroll
      for (int r = 0; r < 4; ++r)
        C[(size_t)(row0 + r) * N + col] = __float2bfloat16(acc[i][j][r] + bj);
    }
  }
}

// ---------------- gemm2: 64x128, BK=64, single-buffer gload_lds, fp32 out -----
__global__ __launch_bounds__(256) void gemm2_c(const __hip_bfloat16* __restrict__ A,
                                               const __hip_bfloat16* __restrict__ B,
                                               const float* __restrict__ bias,
                                               float* __restrict__ C,
                                               int M, int N, int K) {
  __shared__ __align__(16) short Abuf[4096];  // 8 KB
  __shared__ __align__(16) short Bbuf[8192];  // 16 KB -> 24 KB total
  const int tid  = threadIdx.x;
  const int wave = tid >> 6;
  const int lane = tid & 63;
  const int quad = lane >> 4;
  const int l16  = lane & 15;
  const int bm = blockIdx.x * 64;    // M fastest
  const int bn = blockIdx.y * 128;
  const int wm = (wave & 1) * 32;
  const int wn = (wave >> 1) * 64;

  const int srow = tid >> 3;
  const int skh  = tid & 7;
  const int khs  = skh ^ (srow & 7);
  const __hip_bfloat16* Ag[2];
  const __hip_bfloat16* Bg[4];
  int ALo[2], BLo[4];
  #pragma unroll
  for (int l = 0; l < 2; ++l) {
    const int row = l * 32 + srow;
    Ag[l] = A + (size_t)(bm + row) * K + khs * 8;
    ALo[l] = (l * 256 + wave * 64) * 8;
  }
  #pragma unroll
  for (int l = 0; l < 4; ++l) {
    const int row = l * 32 + srow;
    Bg[l] = B + (size_t)(bn + row) * K + khs * 8;
    BLo[l] = (l * 256 + wave * 64) * 8;
  }

  v4f acc[2][4];
  const v4f vz = {0.f, 0.f, 0.f, 0.f};
  #pragma unroll
  for (int i = 0; i < 2; ++i)
    #pragma unroll
    for (int j = 0; j < 4; ++j) acc[i][j] = vz;

  const int sw = l16 & 7;
  const int nk = K >> 6;

  for (int k = 0; k < nk; ++k) {
    const int off = k * 64;
    #pragma unroll
    for (int l = 0; l < 2; ++l) gload16(Ag[l] + off, &Abuf[ALo[l]]);
    #pragma unroll
    for (int l = 0; l < 4; ++l) gload16(Bg[l] + off, &Bbuf[BLo[l]]);
    __syncthreads();
    #pragma unroll
    for (int s = 0; s < 2; ++s) {
      const int khx = (s * 4 + quad) ^ sw;
      v8s af[2], bf[4];
      #pragma unroll
      for (int i = 0; i < 2; ++i)
        af[i] = *(const v8s*)&Abuf[((wm + i * 16 + l16) * 8 + khx) * 8];
      #pragma unroll
      for (int j = 0; j < 4; ++j)
        bf[j] = *(const v8s*)&Bbuf[((wn + j * 16 + l16) * 8 + khx) * 8];
      #pragma unroll
      for (int i = 0; i < 2; ++i)
        #pragma unroll
        for (int j = 0; j < 4; ++j)
          acc[i][j] = __builtin_amdgcn_mfma_f32_16x16x32_bf16(af[i], bf[j], acc[i][j], 0, 0, 0);
    }
    __syncthreads();
  }

  #pragma unroll
  for (int j = 0; j < 4; ++j) {
    const int col = bn + wn + j * 16 + l16;
    const float bj = bias[col];
    #pragma unroll
    for (int i = 0; i < 2; ++i) {
      const int row0 = bm + wm + i * 16 + quad * 4;
      #pragma unroll
      for (int r = 0; r < 4; ++r)
        C[(size_t)(row0 + r) * N + col] = acc[i][j][r] + bj;
    }
  }
}

// ---------------- merged pack kernel (unchanged) ----------------
#define QK_BLOCKS ((2 * S_TOT * 16 * 12) / 256)   // 4608
#define V_BLOCKS  ((3 * 16 * 16 * 8 * 96) / 256)  // 2304
__global__ __launch_bounds__(256) void pack_all(const __hip_bfloat16* __restrict__ qkv,
                                                const float* __restrict__ cos_,
                                                const float* __restrict__ sin_,
                                                short* __restrict__ Qp,
                                                short* __restrict__ Kp,
                                                short* __restrict__ Vp) {
  const int bid = blockIdx.x;
  if (bid < QK_BLOCKS) {
    const int idx = bid * 256 + threadIdx.x;
    const int kd = idx % 12;
    const int h  = (idx / 12) % 16;
    const int s  = (idx / 192) % S_TOT;
    const int p  = idx / (192 * S_TOT);
    const int seg = s >> 10, tb = (s >> 6) & 15, t = s & 63;
    short* out = (p ? Kp : Qp) +
                 ((size_t)(((seg * 16 + h) * 16 + tb) * 12 + kd) * 64 + t) * 8;
    short tmp[8];
    if (kd >= 10) {
      #pragma unroll
      for (int j = 0; j < 8; ++j) tmp[j] = 0;
      *(int4*)out = *(int4*)tmp;
      return;
    }
    const short* row = (const short*)qkv + (size_t)s * TDIM + p * DIM + h * HD;
    const int d0 = kd * 8;
    const v8s xm = *(const v8s*)(row + d0);
    const v8s xr = *(const v8s*)(row + d0 + ((kd < 5) ? 40 : -40));
    const float sgn = (kd < 5) ? -1.f : 1.f;
    const float scale = (p == 0) ? 0.111803398874989485f : 1.0f;
    #pragma unroll
    for (int j = 0; j < 8; ++j) {
      const int d = d0 + j;
      const float v = (bf2f(xm[j]) * cos_[s * HD + d] +
                       sgn * bf2f(xr[j]) * sin_[s * HD + d]) * scale;
      tmp[j] = f2bf(v);
    }
    *(int4*)out = *(int4*)tmp;
  } else {
    const int idx = (bid - QK_BLOCKS) * 256 + threadIdx.x;
    const int d  = idx % 96;
    const int td = (idx / 96) % 8;
    const int tb = (idx / 768) % 16;
    const int h  = (idx / (768 * 16)) % 16;
    const int seg = idx / (768 * 256);
    const int s0 = seg * SEG + tb * 64 + td * 8;
    const short* q = (const short*)qkv;
    short tmp[8];
    if (d < 80) {
      #pragma unroll
      for (int j = 0; j < 8; ++j)
        tmp[j] = q[(size_t)(s0 + j) * TDIM + 2 * DIM + h * HD + d];
    } else {
      const short fill = (d == 80) ? (short)0x3F80 : (short)0;
      #pragma unroll
      for (int j = 0; j < 8; ++j) tmp[j] = fill;
    }
    *(int4*)(Vp + (size_t)idx * 8) = *(int4*)tmp;
  }
}

// ---------------- fused flash MFMA attention (r14 version, unchanged) ---------
__global__ __launch_bounds__(256, 4) void attn_mfma(const short* __restrict__ Qp,
                                                    const short* __restrict__ Kp,
                                                    const short* __restrict__ Vp,
                                                    __hip_bfloat16* __restrict__ out) {
  __shared__ __align__(16) short Ks[64 * 96];
  __shared__ __align__(16) short Vs[64 * 96];
  __shared__ __align__(16) short Ps[4][16 * 68];

  const int qt  = blockIdx.x;
  const int h   = blockIdx.y;
  const int seg = blockIdx.z;
  const int tid  = threadIdx.x;
  const int wave = tid >> 6;
  const int lane = tid & 63;
  const int quad = lane >> 4;
  const int l16  = lane & 15;
  const int sh16 = seg * 16 + h;

  const short* Qg = Qp + (size_t)(sh16 * 16 + qt) * 6144;
  const short* Kg = Kp + (size_t)sh16 * 16 * 6144;
  const short* Vg = Vp + (size_t)sh16 * 16 * 6144;

  v8s af[3];
  #pragma unroll
  for (int ks = 0; ks < 3; ++ks)
    af[ks] = *(const v8s*)(Qg + ((ks * 4 + quad) * 64 + wave * 16 + l16) * 8);

  v8s kr[3], vr[3];
  #pragma unroll
  for (int it = 0; it < 3; ++it) {
    const int o = (it * 256 + tid) * 8;
    kr[it] = *(const v8s*)(Kg + o);
    vr[it] = *(const v8s*)(Vg + o);
  }
  #pragma unroll
  for (int it = 0; it < 3; ++it) {
    const int o = (it * 256 + tid) * 8;
    *(v8s*)&Ks[o] = kr[it];
    *(v8s*)&Vs[o] = vr[it];
  }
  __syncthreads();

  v4f o4[6];
  const v4f vz = {0.f, 0.f, 0.f, 0.f};
  #pragma unroll
  for (int n = 0; n < 6; ++n) o4[n] = vz;

  for (int kb = 0; kb < 16; ++kb) {
    const bool more = (kb + 1 < 16);
    if (more) {
      const size_t base = (size_t)(kb + 1) * 6144;
      #pragma unroll
      for (int it = 0; it < 3; ++it) {
        const int o = (it * 256 + tid) * 8;
        kr[it] = *(const v8s*)(Kg + base + o);
        vr[it] = *(const v8s*)(Vg + base + o);
      }
    }

    v4f s4[4];
    #pragma unroll
    for (int j = 0; j < 4; ++j) {
      s4[j] = vz;
      #pragma unroll
      for (int ks = 0; ks < 3; ++ks) {
        const v8s bf = *(const v8s*)&Ks[((ks * 4 + quad) * 64 + j * 16 + l16) * 8];
        s4[j] = __builtin_amdgcn_mfma_f32_16x16x32_bf16(af[ks], bf, s4[j], 0, 0, 0);
      }
    }

    #pragma unroll
    for (int reg = 0; reg < 4; ++reg)
      #pragma unroll
      for (int j = 0; j < 4; ++j)
        Ps[wave][(quad * 4 + reg) * 68 + j * 16 + l16] = f2bf(__expf(s4[j][reg]));

    v8s pa[2];
    #pragma unroll
    for (int kp = 0; kp < 2; ++kp)
      pa[kp] = *(const v8s*)&Ps[wave][l16 * 68 + kp * 32 + quad * 8];
    #pragma unroll
    for (int n = 0; n < 6; ++n) {
      #pragma unroll
      for (int kp = 0; kp < 2; ++kp) {
        const v8s vb = *(const v8s*)&Vs[((kp * 4 + quad) * 96 + n * 16 + l16) * 8];
        o4[n] = __builtin_amdgcn_mfma_f32_16x16x32_bf16(pa[kp], vb, o4[n], 0, 0, 0);
      }
    }

    __syncthreads();
    if (more) {
      #pragma unroll
      for (int it = 0; it < 3; ++it) {
        const int o = (it * 256 + tid) * 8;
        *(v8s*)&Ks[o] = kr[it];
        *(v8s*)&Vs[o] = vr[it];
      }
    }
    __syncthreads();
  }

  float inv[4];
  #pragma unroll
  for (int r = 0; r < 4; ++r)
    inv[r] = 1.f / __shfl(o4[5][r], quad << 4);
  const int row0 = seg * SEG + qt * 64 + wave * 16 + quad * 4;
  #pragma unroll
  for (int n = 0; n < 5; ++n) {
    const int col = h * HD + n * 16 + l16;
    #pragma unroll
    for (int r = 0; r < 4; ++r)
      out[(size_t)(row0 + r) * DIM + col] = __float2bfloat16(o4[n][r] * inv[r]);
  }
}

extern "C" void kernel_launch(void* const* d_in, const int* in_sizes, int n_in,
                              void* d_out, int out_size, void* d_ws, size_t ws_size,
                              hipStream_t stream) {
  (void)in_sizes; (void)n_in; (void)out_size; (void)ws_size;
  const float* hs     = (const float*)d_in[0];
  const float* cosp   = (const float*)d_in[1];
  const float* sinp   = (const float*)d_in[2];
  const float* qkv_w  = (const float*)d_in[3];
  const float* qkv_b  = (const float*)d_in[4];
  const float* proj_w = (const float*)d_in[5];
  const float* proj_b = (const float*)d_in[6];

  float* out_f = (float*)d_out;
  __hip_bfloat16* qkv_b16 = (__hip_bfloat16*)d_ws;                     // [A]
  __hip_bfloat16* hs_b    = qkv_b16 + (size_t)S_TOT * TDIM;            // [B]
  __hip_bfloat16* qkvw_b  = hs_b + (size_t)S_TOT * DIM;                // [C]
  __hip_bfloat16* projw_b = qkvw_b + (size_t)TDIM * DIM;               // [D]
  short* Qp = (short*)qkvw_b;                                          // alias [C]
  short* Kp = (short*)(projw_b + (size_t)DIM * DIM);                   // [E]
  short* Vp = Kp + (size_t)3 * 16 * 16 * 6144;                         // [F]
  __hip_bfloat16* attn_b = hs_b;                                       // alias [B]

  cvt3<<<(CVT_N1 + CVT_N2 + CVT_N3) / 256, 256, 0, stream>>>(
      hs, qkv_w, proj_w, hs_b, qkvw_b, projw_b);

  gemm1_c<<<dim3(S_TOT / 128, TDIM / 128), 256, 0, stream>>>(
      hs_b, qkvw_b, qkv_b, qkv_b16, S_TOT, TDIM, DIM);

  pack_all<<<QK_BLOCKS + V_BLOCKS, 256, 0, stream>>>(qkv_b16, cosp, sinp, Qp, Kp, Vp);

  attn_mfma<<<dim3(16, NH, 3), 256, 0, stream>>>(Qp, Kp, Vp, attn_b);

  gemm2_c<<<dim3(S_TOT / 64, DIM / 128), 256, 0, stream>>>(
      attn_b, projw_b, proj_b, out_f, S_TOT, DIM, DIM);
}

// Round 3
// 215.400 us; speedup vs baseline: 1.0197x; 1.0197x over previous
//
#include <hip/hip_runtime.h>
#include <hip/hip_bf16.h>

// Round 18: gemm1 -> 256x256 tile, BK=32, 4-deep LDS ring (128 KB dynamic),
// counted vmcnt (never drain-0 in steady state), raw s_barrier. Rationale:
// occupancy is GRID-limited (720 blk @128^2 = 2.8/CU; measured 14% in r15-r17
// regardless of LDS), so only a deep in-block pipeline helps. 4-ring is
// race-free by construction: STAGE(t+3) targets ring (t-1)&3, issued after the
// barrier ending tile t's reads; vmcnt(8) before barrier-1 guarantees tile t
// landed (all waves wait, then barrier). Tail tightens 8->4->0.
// gemm2 reverted to r15's proven reg-staged version. cvt/pack/attn unchanged.
//
// ws layout (r10):
//   [A] qkv_b16: 3072*3840 bf16 (23.6 MB)
//   [B] hs_b   : 3072*1280 bf16 (7.9 MB)  -- reused as attn_b after gemm1
//   [C] qkvw_b : 3840*1280 bf16 (9.8 MB)  -- Qp aliases after gemm1
//   [D] projw_b: 1280*1280 bf16 (3.3 MB)
//   [E] Kp     : 9.4 MB   [F] Vp: 9.4 MB (96-wide, col80 = ones)

#define S_TOT 3072
#define DIM   1280
#define NH    16
#define HD    80
#define SEG   1024
#define TDIM  3840

typedef short v8s __attribute__((ext_vector_type(8)));
typedef float v4f __attribute__((ext_vector_type(4)));

__device__ __forceinline__ short f2bf(float v) {
  __hip_bfloat16 b = __float2bfloat16(v);
  return *reinterpret_cast<short*>(&b);
}

__device__ __forceinline__ float bf2f(short s) {
  unsigned u = ((unsigned)(unsigned short)s) << 16;
  float f;
  __builtin_memcpy(&f, &u, 4);
  return f;
}

// async global->LDS, 16B per lane, wave-uniform LDS base + lane*16 dest
__device__ __forceinline__ void gload16(const void* g, void* lds) {
  __builtin_amdgcn_global_load_lds(
      (const __attribute__((address_space(1))) char*)g,
      (__attribute__((address_space(3))) char*)lds, 16, 0, 0);
}

#define CVT_N1 (S_TOT * DIM / 4)
#define CVT_N2 (TDIM * DIM / 4)
#define CVT_N3 (DIM * DIM / 4)
__global__ __launch_bounds__(256) void cvt3(const float* __restrict__ in1,
                                            const float* __restrict__ in2,
                                            const float* __restrict__ in3,
                                            __hip_bfloat16* __restrict__ o1,
                                            __hip_bfloat16* __restrict__ o2,
                                            __hip_bfloat16* __restrict__ o3) {
  int i = blockIdx.x * 256 + threadIdx.x;
  const float* in;
  __hip_bfloat16* out;
  if (i < CVT_N1) { in = in1; out = o1; }
  else if (i < CVT_N1 + CVT_N2) { in = in2; out = o2; i -= CVT_N1; }
  else { in = in3; out = o3; i -= CVT_N1 + CVT_N2; }
  const float4 v = ((const float4*)in)[i];
  __hip_bfloat162 p0, p1;
  p0.x = __float2bfloat16(v.x); p0.y = __float2bfloat16(v.y);
  p1.x = __float2bfloat16(v.z); p1.y = __float2bfloat16(v.w);
  __hip_bfloat162* o = (__hip_bfloat162*)(out + (size_t)i * 4);
  o[0] = p0; o[1] = p1;
}

// -------- gemm1_p: 256x256 tile, BK=32, 4-ring pipeline, 512 threads ---------
// LDS ring r (16384 shorts): A tile at +0 (256 rows x 4 chunks of 8 shorts),
// B tile at +8192. Linear chunk (row*4 + c) holds global k-chunk c ^ (row&3).
extern __shared__ short ring[];

__global__ __launch_bounds__(512, 2) void gemm1_p(const __hip_bfloat16* __restrict__ A,
                                                  const __hip_bfloat16* __restrict__ B,
                                                  const float* __restrict__ bias,
                                                  __hip_bfloat16* __restrict__ C,
                                                  int M, int N, int K) {
  const int tid  = threadIdx.x;
  const int wave = tid >> 6;
  const int lane = tid & 63;
  const int quad = lane >> 4;
  const int l16  = lane & 15;
  const int wmp  = wave >> 2;        // 0..1 : wave row (128 rows each)
  const int wnp  = wave & 3;         // 0..3 : wave col (64 cols each)
  const int bm = blockIdx.x * 256;
  const int bn = blockIdx.y * 256;

  // staging: thread covers chunk (srow, sc) of each 128-row half
  const int srow = tid >> 2;          // 0..127
  const int sc   = tid & 3;
  const int kc   = sc ^ (srow & 3);   // pre-swizzled source k-chunk
  const short* aA0 = (const short*)A + (size_t)(bm + srow) * K + kc * 8;
  const short* aA1 = aA0 + (size_t)128 * K;
  const short* bB0 = (const short*)B + (size_t)(bn + srow) * K + kc * 8;
  const short* bB1 = bB0 + (size_t)128 * K;
  const int wst = wave * 512;         // wave-uniform LDS chunk base (shorts)

#define STAGE1(t) do {                                   \
    short* rb_ = ring + (((t) & 3) * 16384);             \
    const int ko_ = (t) * 32;                            \
    gload16(aA0 + ko_, rb_ + wst);                       \
    gload16(aA1 + ko_, rb_ + 4096 + wst);                \
    gload16(bB0 + ko_, rb_ + 8192 + wst);                \
    gload16(bB1 + ko_, rb_ + 12288 + wst);               \
  } while (0)

  v4f acc[8][4];
  const v4f vz = {0.f, 0.f, 0.f, 0.f};
  #pragma unroll
  for (int i = 0; i < 8; ++i)
    #pragma unroll
    for (int j = 0; j < 4; ++j) acc[i][j] = vz;

  const int nt  = K >> 5;             // 40 K-tiles of 32
  const int khx = quad ^ (l16 & 3);   // read-side swizzle (row&3 == l16&3)

  STAGE1(0); STAGE1(1); STAGE1(2);    // 12 loads/wave in flight

  for (int t = 0; t < nt; ++t) {
    const int rem = nt - 1 - t;       // stages issued after tile t: min(2,rem)
    if (rem >= 2)      asm volatile("s_waitcnt vmcnt(8)" ::: "memory");
    else if (rem == 1) asm volatile("s_waitcnt vmcnt(4)" ::: "memory");
    else               asm volatile("s_waitcnt vmcnt(0)" ::: "memory");
    __builtin_amdgcn_s_barrier();      // all waves: tile t resident
    __builtin_amdgcn_sched_barrier(0);

    const short* rb2 = ring + ((t & 3) * 16384);
    v8s afr[8], bfr[4];
    #pragma unroll
    for (int i = 0; i < 8; ++i)
      afr[i] = *(const v8s*)&rb2[((wmp * 128 + i * 16 + l16) * 4 + khx) * 8];
    #pragma unroll
    for (int j = 0; j < 4; ++j)
      bfr[j] = *(const v8s*)&rb2[8192 + ((wnp * 64 + j * 16 + l16) * 4 + khx) * 8];
    #pragma unroll
    for (int i = 0; i < 8; ++i)
      #pragma unroll
      for (int j = 0; j < 4; ++j)
        acc[i][j] = __builtin_amdgcn_mfma_f32_16x16x32_bf16(afr[i], bfr[j], acc[i][j], 0, 0, 0);

    __builtin_amdgcn_sched_barrier(0);
    __builtin_amdgcn_s_barrier();      // all waves done reading ring t&3
    __builtin_amdgcn_sched_barrier(0);
    if (t + 3 < nt) STAGE1(t + 3);     // ring (t+3)&3 == (t-1)&3: reads done
  }
#undef STAGE1

  #pragma unroll
  for (int j = 0; j < 4; ++j) {
    const int col = bn + wnp * 64 + j * 16 + l16;
    const float bj = bias[col];
    #pragma unroll
    for (int i = 0; i < 8; ++i) {
      const int row0 = bm + wmp * 128 + i * 16 + quad * 4;
      #pragma unroll
      for (int r = 0; r < 4; ++r)
        C[(size_t)(row0 + r) * N + col] = __float2bfloat16(acc[i][j][r] + bj);
    }
  }
}

// ---------------- gemm2: 64x128, BK=64, r15 reg-staged + XOR swizzle ----------
__global__ __launch_bounds__(256) void gemm2_c(const __hip_bfloat16* __restrict__ A,
                                               const __hip_bfloat16* __restrict__ B,
                                               const float* __restrict__ bias,
                                               float* __restrict__ C,
                                               int M, int N, int K) {
  __shared__ __align__(16) short Abuf[2][4096];  // 8 KB each
  __shared__ __align__(16) short Bbuf[2][8192];  // 16 KB each
  const int tid  = threadIdx.x;
  const int wave = tid >> 6;
  const int lane = tid & 63;
  const int quad = lane >> 4;
  const int l16  = lane & 15;
  const int bm = blockIdx.x * 64;    // M fastest
  const int bn = blockIdx.y * 128;
  const int wm = (wave & 1) * 32;
  const int wn = (wave >> 1) * 64;

  const int srow = tid >> 3;
  const int skh  = tid & 7;
  const __hip_bfloat16* Ag[2];
  const __hip_bfloat16* Bg[4];
  int Ao[2], Bo[4];
  #pragma unroll
  for (int l = 0; l < 2; ++l) {
    const int row = l * 32 + srow;
    Ag[l] = A + (size_t)(bm + row) * K + skh * 8;
    Ao[l] = (row * 8 + (skh ^ (row & 7))) * 8;
  }
  #pragma unroll
  for (int l = 0; l < 4; ++l) {
    const int row = l * 32 + srow;
    Bg[l] = B + (size_t)(bn + row) * K + skh * 8;
    Bo[l] = (row * 8 + (skh ^ (row & 7))) * 8;
  }

  v4f acc[2][4];
  const v4f vz = {0.f, 0.f, 0.f, 0.f};
  #pragma unroll
  for (int i = 0; i < 2; ++i)
    #pragma unroll
    for (int j = 0; j < 4; ++j) acc[i][j] = vz;

  const int sw = l16 & 7;
  const int nk = K >> 6;
  v8s ra[2], rb[4];

  #pragma unroll
  for (int l = 0; l < 2; ++l) ra[l] = *(const v8s*)Ag[l];
  #pragma unroll
  for (int l = 0; l < 4; ++l) rb[l] = *(const v8s*)Bg[l];
  #pragma unroll
  for (int l = 0; l < 2; ++l) *(v8s*)&Abuf[0][Ao[l]] = ra[l];
  #pragma unroll
  for (int l = 0; l < 4; ++l) *(v8s*)&Bbuf[0][Bo[l]] = rb[l];
  __syncthreads();

  for (int k = 0; k < nk; ++k) {
    const int cur = k & 1;
    const bool more = (k + 1 < nk);
    if (more) {
      const int off = (k + 1) * 64;
      #pragma unroll
      for (int l = 0; l < 2; ++l) ra[l] = *(const v8s*)(Ag[l] + off);
      #pragma unroll
      for (int l = 0; l < 4; ++l) rb[l] = *(const v8s*)(Bg[l] + off);
    }
    #pragma unroll
    for (int s = 0; s < 2; ++s) {
      const int khx = (s * 4 + quad) ^ sw;
      v8s af[2], bf[4];
      #pragma unroll
      for (int i = 0; i < 2; ++i)
        af[i] = *(const v8s*)&Abuf[cur][((wm + i * 16 + l16) * 8 + khx) * 8];
      #pragma unroll
      for (int j = 0; j < 4; ++j)
        bf[j] = *(const v8s*)&Bbuf[cur][((wn + j * 16 + l16) * 8 + khx) * 8];
      #pragma unroll
      for (int i = 0; i < 2; ++i)
        #pragma unroll
        for (int j = 0; j < 4; ++j)
          acc[i][j] = __builtin_amdgcn_mfma_f32_16x16x32_bf16(af[i], bf[j], acc[i][j], 0, 0, 0);
    }
    if (more) {
      #pragma unroll
      for (int l = 0; l < 2; ++l) *(v8s*)&Abuf[1 - cur][Ao[l]] = ra[l];
      #pragma unroll
      for (int l = 0; l < 4; ++l) *(v8s*)&Bbuf[1 - cur][Bo[l]] = rb[l];
    }
    __syncthreads();
  }

  #pragma unroll
  for (int j = 0; j < 4; ++j) {
    const int col = bn + wn + j * 16 + l16;
    const float bj = bias[col];
    #pragma unroll
    for (int i = 0; i < 2; ++i) {
      const int row0 = bm + wm + i * 16 + quad * 4;
      #pragma unroll
      for (int r = 0; r < 4; ++r)
        C[(size_t)(row0 + r) * N + col] = acc[i][j][r] + bj;
    }
  }
}

// ---------------- merged pack kernel (unchanged) ----------------
#define QK_BLOCKS ((2 * S_TOT * 16 * 12) / 256)   // 4608
#define V_BLOCKS  ((3 * 16 * 16 * 8 * 96) / 256)  // 2304
__global__ __launch_bounds__(256) void pack_all(const __hip_bfloat16* __restrict__ qkv,
                                                const float* __restrict__ cos_,
                                                const float* __restrict__ sin_,
                                                short* __restrict__ Qp,
                                                short* __restrict__ Kp,
                                                short* __restrict__ Vp) {
  const int bid = blockIdx.x;
  if (bid < QK_BLOCKS) {
    const int idx = bid * 256 + threadIdx.x;
    const int kd = idx % 12;
    const int h  = (idx / 12) % 16;
    const int s  = (idx / 192) % S_TOT;
    const int p  = idx / (192 * S_TOT);
    const int seg = s >> 10, tb = (s >> 6) & 15, t = s & 63;
    short* out = (p ? Kp : Qp) +
                 ((size_t)(((seg * 16 + h) * 16 + tb) * 12 + kd) * 64 + t) * 8;
    short tmp[8];
    if (kd >= 10) {
      #pragma unroll
      for (int j = 0; j < 8; ++j) tmp[j] = 0;
      *(int4*)out = *(int4*)tmp;
      return;
    }
    const short* row = (const short*)qkv + (size_t)s * TDIM + p * DIM + h * HD;
    const int d0 = kd * 8;
    const v8s xm = *(const v8s*)(row + d0);
    const v8s xr = *(const v8s*)(row + d0 + ((kd < 5) ? 40 : -40));
    const float sgn = (kd < 5) ? -1.f : 1.f;
    const float scale = (p == 0) ? 0.111803398874989485f : 1.0f;
    #pragma unroll
    for (int j = 0; j < 8; ++j) {
      const int d = d0 + j;
      const float v = (bf2f(xm[j]) * cos_[s * HD + d] +
                       sgn * bf2f(xr[j]) * sin_[s * HD + d]) * scale;
      tmp[j] = f2bf(v);
    }
    *(int4*)out = *(int4*)tmp;
  } else {
    const int idx = (bid - QK_BLOCKS) * 256 + threadIdx.x;
    const int d  = idx % 96;
    const int td = (idx / 96) % 8;
    const int tb = (idx / 768) % 16;
    const int h  = (idx / (768 * 16)) % 16;
    const int seg = idx / (768 * 256);
    const int s0 = seg * SEG + tb * 64 + td * 8;
    const short* q = (const short*)qkv;
    short tmp[8];
    if (d < 80) {
      #pragma unroll
      for (int j = 0; j < 8; ++j)
        tmp[j] = q[(size_t)(s0 + j) * TDIM + 2 * DIM + h * HD + d];
    } else {
      const short fill = (d == 80) ? (short)0x3F80 : (short)0;
      #pragma unroll
      for (int j = 0; j < 8; ++j) tmp[j] = fill;
    }
    *(int4*)(Vp + (size_t)idx * 8) = *(int4*)tmp;
  }
}

// ---------------- fused flash MFMA attention (r14 version, unchanged) ---------
__global__ __launch_bounds__(256, 4) void attn_mfma(const short* __restrict__ Qp,
                                                    const short* __restrict__ Kp,
                                                    const short* __restrict__ Vp,
                                                    __hip_bfloat16* __restrict__ out) {
  __shared__ __align__(16) short Ks[64 * 96];
  __shared__ __align__(16) short Vs[64 * 96];
  __shared__ __align__(16) short Ps[4][16 * 68];

  const int qt  = blockIdx.x;
  const int h   = blockIdx.y;
  const int seg = blockIdx.z;
  const int tid  = threadIdx.x;
  const int wave = tid >> 6;
  const int lane = tid & 63;
  const int quad = lane >> 4;
  const int l16  = lane & 15;
  const int sh16 = seg * 16 + h;

  const short* Qg = Qp + (size_t)(sh16 * 16 + qt) * 6144;
  const short* Kg = Kp + (size_t)sh16 * 16 * 6144;
  const short* Vg = Vp + (size_t)sh16 * 16 * 6144;

  v8s af[3];
  #pragma unroll
  for (int ks = 0; ks < 3; ++ks)
    af[ks] = *(const v8s*)(Qg + ((ks * 4 + quad) * 64 + wave * 16 + l16) * 8);

  v8s kr[3], vr[3];
  #pragma unroll
  for (int it = 0; it < 3; ++it) {
    const int o = (it * 256 + tid) * 8;
    kr[it] = *(const v8s*)(Kg + o);
    vr[it] = *(const v8s*)(Vg + o);
  }
  #pragma unroll
  for (int it = 0; it < 3; ++it) {
    const int o = (it * 256 + tid) * 8;
    *(v8s*)&Ks[o] = kr[it];
    *(v8s*)&Vs[o] = vr[it];
  }
  __syncthreads();

  v4f o4[6];
  const v4f vz = {0.f, 0.f, 0.f, 0.f};
  #pragma unroll
  for (int n = 0; n < 6; ++n) o4[n] = vz;

  for (int kb = 0; kb < 16; ++kb) {
    const bool more = (kb + 1 < 16);
    if (more) {
      const size_t base = (size_t)(kb + 1) * 6144;
      #pragma unroll
      for (int it = 0; it < 3; ++it) {
        const int o = (it * 256 + tid) * 8;
        kr[it] = *(const v8s*)(Kg + base + o);
        vr[it] = *(const v8s*)(Vg + base + o);
      }
    }

    v4f s4[4];
    #pragma unroll
    for (int j = 0; j < 4; ++j) {
      s4[j] = vz;
      #pragma unroll
      for (int ks = 0; ks < 3; ++ks) {
        const v8s bf = *(const v8s*)&Ks[((ks * 4 + quad) * 64 + j * 16 + l16) * 8];
        s4[j] = __builtin_amdgcn_mfma_f32_16x16x32_bf16(af[ks], bf, s4[j], 0, 0, 0);
      }
    }

    #pragma unroll
    for (int reg = 0; reg < 4; ++reg)
      #pragma unroll
      for (int j = 0; j < 4; ++j)
        Ps[wave][(quad * 4 + reg) * 68 + j * 16 + l16] = f2bf(__expf(s4[j][reg]));

    v8s pa[2];
    #pragma unroll
    for (int kp = 0; kp < 2; ++kp)
      pa[kp] = *(const v8s*)&Ps[wave][l16 * 68 + kp * 32 + quad * 8];
    #pragma unroll
    for (int n = 0; n < 6; ++n) {
      #pragma unroll
      for (int kp = 0; kp < 2; ++kp) {
        const v8s vb = *(const v8s*)&Vs[((kp * 4 + quad) * 96 + n * 16 + l16) * 8];
        o4[n] = __builtin_amdgcn_mfma_f32_16x16x32_bf16(pa[kp], vb, o4[n], 0, 0, 0);
      }
    }

    __syncthreads();
    if (more) {
      #pragma unroll
      for (int it = 0; it < 3; ++it) {
        const int o = (it * 256 + tid) * 8;
        *(v8s*)&Ks[o] = kr[it];
        *(v8s*)&Vs[o] = vr[it];
      }
    }
    __syncthreads();
  }

  float inv[4];
  #pragma unroll
  for (int r = 0; r < 4; ++r)
    inv[r] = 1.f / __shfl(o4[5][r], quad << 4);
  const int row0 = seg * SEG + qt * 64 + wave * 16 + quad * 4;
  #pragma unroll
  for (int n = 0; n < 5; ++n) {
    const int col = h * HD + n * 16 + l16;
    #pragma unroll
    for (int r = 0; r < 4; ++r)
      out[(size_t)(row0 + r) * DIM + col] = __float2bfloat16(o4[n][r] * inv[r]);
  }
}

extern "C" void kernel_launch(void* const* d_in, const int* in_sizes, int n_in,
                              void* d_out, int out_size, void* d_ws, size_t ws_size,
                              hipStream_t stream) {
  (void)in_sizes; (void)n_in; (void)out_size; (void)ws_size;
  const float* hs     = (const float*)d_in[0];
  const float* cosp   = (const float*)d_in[1];
  const float* sinp   = (const float*)d_in[2];
  const float* qkv_w  = (const float*)d_in[3];
  const float* qkv_b  = (const float*)d_in[4];
  const float* proj_w = (const float*)d_in[5];
  const float* proj_b = (const float*)d_in[6];

  float* out_f = (float*)d_out;
  __hip_bfloat16* qkv_b16 = (__hip_bfloat16*)d_ws;                     // [A]
  __hip_bfloat16* hs_b    = qkv_b16 + (size_t)S_TOT * TDIM;            // [B]
  __hip_bfloat16* qkvw_b  = hs_b + (size_t)S_TOT * DIM;                // [C]
  __hip_bfloat16* projw_b = qkvw_b + (size_t)TDIM * DIM;               // [D]
  short* Qp = (short*)qkvw_b;                                          // alias [C]
  short* Kp = (short*)(projw_b + (size_t)DIM * DIM);                   // [E]
  short* Vp = Kp + (size_t)3 * 16 * 16 * 6144;                         // [F]
  __hip_bfloat16* attn_b = hs_b;                                       // alias [B]

  static bool attr_set = false;
  if (!attr_set) {
    hipFuncSetAttribute((const void*)gemm1_p,
                        hipFuncAttributeMaxDynamicSharedMemorySize, 131072);
    attr_set = true;
  }

  cvt3<<<(CVT_N1 + CVT_N2 + CVT_N3) / 256, 256, 0, stream>>>(
      hs, qkv_w, proj_w, hs_b, qkvw_b, projw_b);

  gemm1_p<<<dim3(S_TOT / 256, TDIM / 256), 512, 131072, stream>>>(
      hs_b, qkvw_b, qkv_b, qkv_b16, S_TOT, TDIM, DIM);

  pack_all<<<QK_BLOCKS + V_BLOCKS, 256, 0, stream>>>(qkv_b16, cosp, sinp, Qp, Kp, Vp);

  attn_mfma<<<dim3(16, NH, 3), 256, 0, stream>>>(Qp, Kp, Vp, attn_b);

  gemm2_c<<<dim3(S_TOT / 64, DIM / 128), 256, 0, stream>>>(
      attn_b, projw_b, proj_b, out_f, S_TOT, DIM, DIM);
}

// Round 4
// 213.660 us; speedup vs baseline: 1.0280x; 1.0081x over previous
//
#include <hip/hip_runtime.h>
#include <hip/hip_bf16.h>

// Round 19: XCD-L2 reuse theory. r15-r18 all land 47-57us despite wildly
// different schedules -> shared ceiling = L2-miss panel refetch (~460MB L3-side
// traffic @ ~9TB/s). Blocks sharing A/B panels are round-robin scattered over
// 8 non-coherent XCD L2s. Fixes:
//  (1) gemm1: bijective 2D XCD region map (xcd=l%8 owns a 3x8 or 3x7+spill
//      rectangle of the 12x15 tile grid; per-XCD working set ~2.6MB < 4MB L2).
//  (2) gemm1: extended XOR swizzle (row&3)^((row>>2)&3) kills r18's 4-way
//      read conflict (2.76M -> ~0); setprio(1) around MFMA cluster.
//  (3) attn: 1D grid 768; each XCD owns 6 complete (seg,h) groups so the
//      384KB K/V panel is L2-resident and reused by its 16 qt-blocks.
// gemm2/pack/cvt unchanged (r15-proven).
//
// ws layout (r10):
//   [A] qkv_b16: 3072*3840 bf16 (23.6 MB)
//   [B] hs_b   : 3072*1280 bf16 (7.9 MB)  -- reused as attn_b after gemm1
//   [C] qkvw_b : 3840*1280 bf16 (9.8 MB)  -- Qp aliases after gemm1
//   [D] projw_b: 1280*1280 bf16 (3.3 MB)
//   [E] Kp     : 9.4 MB   [F] Vp: 9.4 MB (96-wide, col80 = ones)

#define S_TOT 3072
#define DIM   1280
#define NH    16
#define HD    80
#define SEG   1024
#define TDIM  3840

typedef short v8s __attribute__((ext_vector_type(8)));
typedef float v4f __attribute__((ext_vector_type(4)));

__device__ __forceinline__ short f2bf(float v) {
  __hip_bfloat16 b = __float2bfloat16(v);
  return *reinterpret_cast<short*>(&b);
}

__device__ __forceinline__ float bf2f(short s) {
  unsigned u = ((unsigned)(unsigned short)s) << 16;
  float f;
  __builtin_memcpy(&f, &u, 4);
  return f;
}

// async global->LDS, 16B per lane, wave-uniform LDS base + lane*16 dest
__device__ __forceinline__ void gload16(const void* g, void* lds) {
  __builtin_amdgcn_global_load_lds(
      (const __attribute__((address_space(1))) char*)g,
      (__attribute__((address_space(3))) char*)lds, 16, 0, 0);
}

#define CVT_N1 (S_TOT * DIM / 4)
#define CVT_N2 (TDIM * DIM / 4)
#define CVT_N3 (DIM * DIM / 4)
__global__ __launch_bounds__(256) void cvt3(const float* __restrict__ in1,
                                            const float* __restrict__ in2,
                                            const float* __restrict__ in3,
                                            __hip_bfloat16* __restrict__ o1,
                                            __hip_bfloat16* __restrict__ o2,
                                            __hip_bfloat16* __restrict__ o3) {
  int i = blockIdx.x * 256 + threadIdx.x;
  const float* in;
  __hip_bfloat16* out;
  if (i < CVT_N1) { in = in1; out = o1; }
  else if (i < CVT_N1 + CVT_N2) { in = in2; out = o2; i -= CVT_N1; }
  else { in = in3; out = o3; i -= CVT_N1 + CVT_N2; }
  const float4 v = ((const float4*)in)[i];
  __hip_bfloat162 p0, p1;
  p0.x = __float2bfloat16(v.x); p0.y = __float2bfloat16(v.y);
  p1.x = __float2bfloat16(v.z); p1.y = __float2bfloat16(v.w);
  __hip_bfloat162* o = (__hip_bfloat162*)(out + (size_t)i * 4);
  o[0] = p0; o[1] = p1;
}

// -------- gemm1_p: 256x256 tile, BK=32, 4-ring pipeline, 512 threads ---------
// LDS ring r (16384 shorts): A tile at +0, B tile at +8192.
// Linear chunk (row*4 + c) holds global k-chunk c ^ (row&3) ^ ((row>>2)&3).
// Grid: 1D 180 blocks; 2D XCD region mapping (12x15 tile grid hard-coded).
extern __shared__ short ring[];

__global__ __launch_bounds__(512, 2) void gemm1_p(const __hip_bfloat16* __restrict__ A,
                                                  const __hip_bfloat16* __restrict__ B,
                                                  const float* __restrict__ bias,
                                                  __hip_bfloat16* __restrict__ C,
                                                  int M, int N, int K) {
  const int tid  = threadIdx.x;
  const int wave = tid >> 6;
  const int lane = tid & 63;
  const int quad = lane >> 4;
  const int l16  = lane & 15;
  const int wmp  = wave >> 2;        // 0..1 : wave row (128 rows each)
  const int wnp  = wave & 3;         // 0..3 : wave col (64 cols each)

  // XCD region map: xcd = l%8 (empirical round-robin). rb=xcd&3 -> rows
  // 3rb..3rb+2; cb=xcd>>2 -> cols 0..7 (cap 24, gets 23) or 8..14 (cap 21,
  // gets 22; spill s=21 fills the cb0 region's unused slot (3rb+2, 7)).
  {
  }
  const int l   = blockIdx.x;
  const int xcd = l & 7;
  const int sq  = l >> 3;
  const int rb  = xcd & 3;
  const int cb  = xcd >> 2;
  int bxi, byi;
  if (cb == 0)       { bxi = 3 * rb + sq % 3; byi = sq / 3; }
  else if (sq < 21)  { bxi = 3 * rb + sq % 3; byi = 8 + sq / 3; }
  else               { bxi = 3 * rb + 2;      byi = 7; }
  const int bm = bxi * 256;
  const int bn = byi * 256;

  // staging: thread covers chunk (srow, sc) of each 128-row half
  const int srow = tid >> 2;          // 0..127
  const int sc   = tid & 3;
  const int kc   = sc ^ (srow & 3) ^ ((srow >> 2) & 3);  // pre-swizzled source
  const short* aA0 = (const short*)A + (size_t)(bm + srow) * K + kc * 8;
  const short* aA1 = aA0 + (size_t)128 * K;
  const short* bB0 = (const short*)B + (size_t)(bn + srow) * K + kc * 8;
  const short* bB1 = bB0 + (size_t)128 * K;
  const int wst = wave * 512;         // wave-uniform LDS chunk base (shorts)

#define STAGE1(t) do {                                   \
    short* rb_ = ring + (((t) & 3) * 16384);             \
    const int ko_ = (t) * 32;                            \
    gload16(aA0 + ko_, rb_ + wst);                       \
    gload16(aA1 + ko_, rb_ + 4096 + wst);                \
    gload16(bB0 + ko_, rb_ + 8192 + wst);                \
    gload16(bB1 + ko_, rb_ + 12288 + wst);               \
  } while (0)

  v4f acc[8][4];
  const v4f vz = {0.f, 0.f, 0.f, 0.f};
  #pragma unroll
  for (int i = 0; i < 8; ++i)
    #pragma unroll
    for (int j = 0; j < 4; ++j) acc[i][j] = vz;

  const int nt  = K >> 5;             // 40 K-tiles of 32
  // read-side swizzle: row&3 == l16&3, (row>>2)&3 == (l16>>2)&3 for both A,B
  const int khx = quad ^ (l16 & 3) ^ ((l16 >> 2) & 3);

  STAGE1(0); STAGE1(1); STAGE1(2);    // 12 loads/wave in flight

  for (int t = 0; t < nt; ++t) {
    const int rem = nt - 1 - t;       // stages issued after tile t: min(2,rem)
    if (rem >= 2)      asm volatile("s_waitcnt vmcnt(8)" ::: "memory");
    else if (rem == 1) asm volatile("s_waitcnt vmcnt(4)" ::: "memory");
    else               asm volatile("s_waitcnt vmcnt(0)" ::: "memory");
    __builtin_amdgcn_s_barrier();      // all waves: tile t resident
    __builtin_amdgcn_sched_barrier(0);

    const short* rb2 = ring + ((t & 3) * 16384);
    v8s afr[8], bfr[4];
    #pragma unroll
    for (int i = 0; i < 8; ++i)
      afr[i] = *(const v8s*)&rb2[((wmp * 128 + i * 16 + l16) * 4 + khx) * 8];
    #pragma unroll
    for (int j = 0; j < 4; ++j)
      bfr[j] = *(const v8s*)&rb2[8192 + ((wnp * 64 + j * 16 + l16) * 4 + khx) * 8];
    __builtin_amdgcn_s_setprio(1);
    #pragma unroll
    for (int i = 0; i < 8; ++i)
      #pragma unroll
      for (int j = 0; j < 4; ++j)
        acc[i][j] = __builtin_amdgcn_mfma_f32_16x16x32_bf16(afr[i], bfr[j], acc[i][j], 0, 0, 0);
    __builtin_amdgcn_s_setprio(0);

    __builtin_amdgcn_sched_barrier(0);
    __builtin_amdgcn_s_barrier();      // all waves done reading ring t&3
    __builtin_amdgcn_sched_barrier(0);
    if (t + 3 < nt) STAGE1(t + 3);     // ring (t+3)&3 == (t-1)&3: reads done
  }
#undef STAGE1

  #pragma unroll
  for (int j = 0; j < 4; ++j) {
    const int col = bn + wnp * 64 + j * 16 + l16;
    const float bj = bias[col];
    #pragma unroll
    for (int i = 0; i < 8; ++i) {
      const int row0 = bm + wmp * 128 + i * 16 + quad * 4;
      #pragma unroll
      for (int r = 0; r < 4; ++r)
        C[(size_t)(row0 + r) * N + col] = __float2bfloat16(acc[i][j][r] + bj);
    }
  }
}

// ---------------- gemm2: 64x128, BK=64, r15 reg-staged + XOR swizzle ----------
__global__ __launch_bounds__(256) void gemm2_c(const __hip_bfloat16* __restrict__ A,
                                               const __hip_bfloat16* __restrict__ B,
                                               const float* __restrict__ bias,
                                               float* __restrict__ C,
                                               int M, int N, int K) {
  __shared__ __align__(16) short Abuf[2][4096];  // 8 KB each
  __shared__ __align__(16) short Bbuf[2][8192];  // 16 KB each
  const int tid  = threadIdx.x;
  const int wave = tid >> 6;
  const int lane = tid & 63;
  const int quad = lane >> 4;
  const int l16  = lane & 15;
  const int bm = blockIdx.x * 64;    // M fastest
  const int bn = blockIdx.y * 128;
  const int wm = (wave & 1) * 32;
  const int wn = (wave >> 1) * 64;

  const int srow = tid >> 3;
  const int skh  = tid & 7;
  const __hip_bfloat16* Ag[2];
  const __hip_bfloat16* Bg[4];
  int Ao[2], Bo[4];
  #pragma unroll
  for (int l = 0; l < 2; ++l) {
    const int row = l * 32 + srow;
    Ag[l] = A + (size_t)(bm + row) * K + skh * 8;
    Ao[l] = (row * 8 + (skh ^ (row & 7))) * 8;
  }
  #pragma unroll
  for (int l = 0; l < 4; ++l) {
    const int row = l * 32 + srow;
    Bg[l] = B + (size_t)(bn + row) * K + skh * 8;
    Bo[l] = (row * 8 + (skh ^ (row & 7))) * 8;
  }

  v4f acc[2][4];
  const v4f vz = {0.f, 0.f, 0.f, 0.f};
  #pragma unroll
  for (int i = 0; i < 2; ++i)
    #pragma unroll
    for (int j = 0; j < 4; ++j) acc[i][j] = vz;

  const int sw = l16 & 7;
  const int nk = K >> 6;
  v8s ra[2], rb[4];

  #pragma unroll
  for (int l = 0; l < 2; ++l) ra[l] = *(const v8s*)Ag[l];
  #pragma unroll
  for (int l = 0; l < 4; ++l) rb[l] = *(const v8s*)Bg[l];
  #pragma unroll
  for (int l = 0; l < 2; ++l) *(v8s*)&Abuf[0][Ao[l]] = ra[l];
  #pragma unroll
  for (int l = 0; l < 4; ++l) *(v8s*)&Bbuf[0][Bo[l]] = rb[l];
  __syncthreads();

  for (int k = 0; k < nk; ++k) {
    const int cur = k & 1;
    const bool more = (k + 1 < nk);
    if (more) {
      const int off = (k + 1) * 64;
      #pragma unroll
      for (int l = 0; l < 2; ++l) ra[l] = *(const v8s*)(Ag[l] + off);
      #pragma unroll
      for (int l = 0; l < 4; ++l) rb[l] = *(const v8s*)(Bg[l] + off);
    }
    #pragma unroll
    for (int s = 0; s < 2; ++s) {
      const int khx = (s * 4 + quad) ^ sw;
      v8s af[2], bf[4];
      #pragma unroll
      for (int i = 0; i < 2; ++i)
        af[i] = *(const v8s*)&Abuf[cur][((wm + i * 16 + l16) * 8 + khx) * 8];
      #pragma unroll
      for (int j = 0; j < 4; ++j)
        bf[j] = *(const v8s*)&Bbuf[cur][((wn + j * 16 + l16) * 8 + khx) * 8];
      #pragma unroll
      for (int i = 0; i < 2; ++i)
        #pragma unroll
        for (int j = 0; j < 4; ++j)
          acc[i][j] = __builtin_amdgcn_mfma_f32_16x16x32_bf16(af[i], bf[j], acc[i][j], 0, 0, 0);
    }
    if (more) {
      #pragma unroll
      for (int l = 0; l < 2; ++l) *(v8s*)&Abuf[1 - cur][Ao[l]] = ra[l];
      #pragma unroll
      for (int l = 0; l < 4; ++l) *(v8s*)&Bbuf[1 - cur][Bo[l]] = rb[l];
    }
    __syncthreads();
  }

  #pragma unroll
  for (int j = 0; j < 4; ++j) {
    const int col = bn + wn + j * 16 + l16;
    const float bj = bias[col];
    #pragma unroll
    for (int i = 0; i < 2; ++i) {
      const int row0 = bm + wm + i * 16 + quad * 4;
      #pragma unroll
      for (int r = 0; r < 4; ++r)
        C[(size_t)(row0 + r) * N + col] = acc[i][j][r] + bj;
    }
  }
}

// ---------------- merged pack kernel (unchanged) ----------------
#define QK_BLOCKS ((2 * S_TOT * 16 * 12) / 256)   // 4608
#define V_BLOCKS  ((3 * 16 * 16 * 8 * 96) / 256)  // 2304
__global__ __launch_bounds__(256) void pack_all(const __hip_bfloat16* __restrict__ qkv,
                                                const float* __restrict__ cos_,
                                                const float* __restrict__ sin_,
                                                short* __restrict__ Qp,
                                                short* __restrict__ Kp,
                                                short* __restrict__ Vp) {
  const int bid = blockIdx.x;
  if (bid < QK_BLOCKS) {
    const int idx = bid * 256 + threadIdx.x;
    const int kd = idx % 12;
    const int h  = (idx / 12) % 16;
    const int s  = (idx / 192) % S_TOT;
    const int p  = idx / (192 * S_TOT);
    const int seg = s >> 10, tb = (s >> 6) & 15, t = s & 63;
    short* out = (p ? Kp : Qp) +
                 ((size_t)(((seg * 16 + h) * 16 + tb) * 12 + kd) * 64 + t) * 8;
    short tmp[8];
    if (kd >= 10) {
      #pragma unroll
      for (int j = 0; j < 8; ++j) tmp[j] = 0;
      *(int4*)out = *(int4*)tmp;
      return;
    }
    const short* row = (const short*)qkv + (size_t)s * TDIM + p * DIM + h * HD;
    const int d0 = kd * 8;
    const v8s xm = *(const v8s*)(row + d0);
    const v8s xr = *(const v8s*)(row + d0 + ((kd < 5) ? 40 : -40));
    const float sgn = (kd < 5) ? -1.f : 1.f;
    const float scale = (p == 0) ? 0.111803398874989485f : 1.0f;
    #pragma unroll
    for (int j = 0; j < 8; ++j) {
      const int d = d0 + j;
      const float v = (bf2f(xm[j]) * cos_[s * HD + d] +
                       sgn * bf2f(xr[j]) * sin_[s * HD + d]) * scale;
      tmp[j] = f2bf(v);
    }
    *(int4*)out = *(int4*)tmp;
  } else {
    const int idx = (bid - QK_BLOCKS) * 256 + threadIdx.x;
    const int d  = idx % 96;
    const int td = (idx / 96) % 8;
    const int tb = (idx / 768) % 16;
    const int h  = (idx / (768 * 16)) % 16;
    const int seg = idx / (768 * 256);
    const int s0 = seg * SEG + tb * 64 + td * 8;
    const short* q = (const short*)qkv;
    short tmp[8];
    if (d < 80) {
      #pragma unroll
      for (int j = 0; j < 8; ++j)
        tmp[j] = q[(size_t)(s0 + j) * TDIM + 2 * DIM + h * HD + d];
    } else {
      const short fill = (d == 80) ? (short)0x3F80 : (short)0;
      #pragma unroll
      for (int j = 0; j < 8; ++j) tmp[j] = fill;
    }
    *(int4*)(Vp + (size_t)idx * 8) = *(int4*)tmp;
  }
}

// -------- fused flash MFMA attention (r14 compute; XCD group mapping) --------
// 1D grid 768. xcd = l%8 owns 6 complete (seg,h) groups; all 16 qt-blocks of a
// group land on the same XCD -> its 384KB K/V panel is L2-resident and reused.
__global__ __launch_bounds__(256, 4) void attn_mfma(const short* __restrict__ Qp,
                                                    const short* __restrict__ Kp,
                                                    const short* __restrict__ Vp,
                                                    __hip_bfloat16* __restrict__ out) {
  __shared__ __align__(16) short Ks[64 * 96];
  __shared__ __align__(16) short Vs[64 * 96];
  __shared__ __align__(16) short Ps[4][16 * 68];

  const int l   = blockIdx.x;
  const int xcd = l & 7;
  const int j8  = l >> 3;            // 0..95
  const int g   = xcd * 6 + (j8 >> 4);  // group 0..47  (= seg*16 + h)
  const int qt  = j8 & 15;
  const int h   = g & 15;
  const int seg = g >> 4;
  const int tid  = threadIdx.x;
  const int wave = tid >> 6;
  const int lane = tid & 63;
  const int quad = lane >> 4;
  const int l16  = lane & 15;
  const int sh16 = g;

  const short* Qg = Qp + (size_t)(sh16 * 16 + qt) * 6144;
  const short* Kg = Kp + (size_t)sh16 * 16 * 6144;
  const short* Vg = Vp + (size_t)sh16 * 16 * 6144;

  v8s af[3];
  #pragma unroll
  for (int ks = 0; ks < 3; ++ks)
    af[ks] = *(const v8s*)(Qg + ((ks * 4 + quad) * 64 + wave * 16 + l16) * 8);

  v8s kr[3], vr[3];
  #pragma unroll
  for (int it = 0; it < 3; ++it) {
    const int o = (it * 256 + tid) * 8;
    kr[it] = *(const v8s*)(Kg + o);
    vr[it] = *(const v8s*)(Vg + o);
  }
  #pragma unroll
  for (int it = 0; it < 3; ++it) {
    const int o = (it * 256 + tid) * 8;
    *(v8s*)&Ks[o] = kr[it];
    *(v8s*)&Vs[o] = vr[it];
  }
  __syncthreads();

  v4f o4[6];
  const v4f vz = {0.f, 0.f, 0.f, 0.f};
  #pragma unroll
  for (int n = 0; n < 6; ++n) o4[n] = vz;

  for (int kb = 0; kb < 16; ++kb) {
    const bool more = (kb + 1 < 16);
    if (more) {
      const size_t base = (size_t)(kb + 1) * 6144;
      #pragma unroll
      for (int it = 0; it < 3; ++it) {
        const int o = (it * 256 + tid) * 8;
        kr[it] = *(const v8s*)(Kg + base + o);
        vr[it] = *(const v8s*)(Vg + base + o);
      }
    }

    v4f s4[4];
    #pragma unroll
    for (int j = 0; j < 4; ++j) {
      s4[j] = vz;
      #pragma unroll
      for (int ks = 0; ks < 3; ++ks) {
        const v8s bf = *(const v8s*)&Ks[((ks * 4 + quad) * 64 + j * 16 + l16) * 8];
        s4[j] = __builtin_amdgcn_mfma_f32_16x16x32_bf16(af[ks], bf, s4[j], 0, 0, 0);
      }
    }

    #pragma unroll
    for (int reg = 0; reg < 4; ++reg)
      #pragma unroll
      for (int j = 0; j < 4; ++j)
        Ps[wave][(quad * 4 + reg) * 68 + j * 16 + l16] = f2bf(__expf(s4[j][reg]));

    v8s pa[2];
    #pragma unroll
    for (int kp = 0; kp < 2; ++kp)
      pa[kp] = *(const v8s*)&Ps[wave][l16 * 68 + kp * 32 + quad * 8];
    #pragma unroll
    for (int n = 0; n < 6; ++n) {
      #pragma unroll
      for (int kp = 0; kp < 2; ++kp) {
        const v8s vb = *(const v8s*)&Vs[((kp * 4 + quad) * 96 + n * 16 + l16) * 8];
        o4[n] = __builtin_amdgcn_mfma_f32_16x16x32_bf16(pa[kp], vb, o4[n], 0, 0, 0);
      }
    }

    __syncthreads();
    if (more) {
      #pragma unroll
      for (int it = 0; it < 3; ++it) {
        const int o = (it * 256 + tid) * 8;
        *(v8s*)&Ks[o] = kr[it];
        *(v8s*)&Vs[o] = vr[it];
      }
    }
    __syncthreads();
  }

  float inv[4];
  #pragma unroll
  for (int r = 0; r < 4; ++r)
    inv[r] = 1.f / __shfl(o4[5][r], quad << 4);
  const int row0 = seg * SEG + qt * 64 + wave * 16 + quad * 4;
  #pragma unroll
  for (int n = 0; n < 5; ++n) {
    const int col = h * HD + n * 16 + l16;
    #pragma unroll
    for (int r = 0; r < 4; ++r)
      out[(size_t)(row0 + r) * DIM + col] = __float2bfloat16(o4[n][r] * inv[r]);
  }
}

extern "C" void kernel_launch(void* const* d_in, const int* in_sizes, int n_in,
                              void* d_out, int out_size, void* d_ws, size_t ws_size,
                              hipStream_t stream) {
  (void)in_sizes; (void)n_in; (void)out_size; (void)ws_size;
  const float* hs     = (const float*)d_in[0];
  const float* cosp   = (const float*)d_in[1];
  const float* sinp   = (const float*)d_in[2];
  const float* qkv_w  = (const float*)d_in[3];
  const float* qkv_b  = (const float*)d_in[4];
  const float* proj_w = (const float*)d_in[5];
  const float* proj_b = (const float*)d_in[6];

  float* out_f = (float*)d_out;
  __hip_bfloat16* qkv_b16 = (__hip_bfloat16*)d_ws;                     // [A]
  __hip_bfloat16* hs_b    = qkv_b16 + (size_t)S_TOT * TDIM;            // [B]
  __hip_bfloat16* qkvw_b  = hs_b + (size_t)S_TOT * DIM;                // [C]
  __hip_bfloat16* projw_b = qkvw_b + (size_t)TDIM * DIM;               // [D]
  short* Qp = (short*)qkvw_b;                                          // alias [C]
  short* Kp = (short*)(projw_b + (size_t)DIM * DIM);                   // [E]
  short* Vp = Kp + (size_t)3 * 16 * 16 * 6144;                         // [F]
  __hip_bfloat16* attn_b = hs_b;                                       // alias [B]

  static bool attr_set = false;
  if (!attr_set) {
    hipFuncSetAttribute((const void*)gemm1_p,
                        hipFuncAttributeMaxDynamicSharedMemorySize, 131072);
    attr_set = true;
  }

  cvt3<<<(CVT_N1 + CVT_N2 + CVT_N3) / 256, 256, 0, stream>>>(
      hs, qkv_w, proj_w, hs_b, qkvw_b, projw_b);

  gemm1_p<<<dim3(180), 512, 131072, stream>>>(
      hs_b, qkvw_b, qkv_b, qkv_b16, S_TOT, TDIM, DIM);

  pack_all<<<QK_BLOCKS + V_BLOCKS, 256, 0, stream>>>(qkv_b16, cosp, sinp, Qp, Kp, Vp);

  attn_mfma<<<dim3(768), 256, 0, stream>>>(Qp, Kp, Vp, attn_b);

  gemm2_c<<<dim3(S_TOT / 64, DIM / 128), 256, 0, stream>>>(
      attn_b, projw_b, proj_b, out_f, S_TOT, DIM, DIM);
}

// Round 5
// 202.126 us; speedup vs baseline: 1.0867x; 1.0571x over previous
//
#include <hip/hip_runtime.h>
#include <hip/hip_bf16.h>

// Round 20: consolidation. Findings from r16-r19: (a) L2/L3 panel-refetch is
// NOT the gemm1 time limiter (r19 cut FETCH 46->28MB, time got worse);
// (b) the r18/r19 ring conflicts (2.76M, bit-identical across swizzle edits)
// are structural to that staging, not the frag reads; (c) attn XCD group map
// is a real ~11us win (r19 non-gemm1 time 158.5->147.7) -> keep it.
// gemm1: back to r15's proven reg-staged 1-barrier dbuf schedule, but BK=32
// and 32KB LDS -> 5 blocks/CU cap, all 720 blocks co-resident (zero tail,
// max m114 wave-overlap). 4-chunk swizzle done right: chunk c stored at
// c ^ (row&3) ^ ((row>>2)&1) -> every lane-octet spans all 8 bank groups.
//
// ws layout (r10):
//   [A] qkv_b16: 3072*3840 bf16 (23.6 MB)
//   [B] hs_b   : 3072*1280 bf16 (7.9 MB)  -- reused as attn_b after gemm1
//   [C] qkvw_b : 3840*1280 bf16 (9.8 MB)  -- Qp aliases after gemm1
//   [D] projw_b: 1280*1280 bf16 (3.3 MB)
//   [E] Kp     : 9.4 MB   [F] Vp: 9.4 MB (96-wide, col80 = ones)

#define S_TOT 3072
#define DIM   1280
#define NH    16
#define HD    80
#define SEG   1024
#define TDIM  3840

typedef short v8s __attribute__((ext_vector_type(8)));
typedef float v4f __attribute__((ext_vector_type(4)));

__device__ __forceinline__ short f2bf(float v) {
  __hip_bfloat16 b = __float2bfloat16(v);
  return *reinterpret_cast<short*>(&b);
}

__device__ __forceinline__ float bf2f(short s) {
  unsigned u = ((unsigned)(unsigned short)s) << 16;
  float f;
  __builtin_memcpy(&f, &u, 4);
  return f;
}

#define CVT_N1 (S_TOT * DIM / 4)
#define CVT_N2 (TDIM * DIM / 4)
#define CVT_N3 (DIM * DIM / 4)
__global__ __launch_bounds__(256) void cvt3(const float* __restrict__ in1,
                                            const float* __restrict__ in2,
                                            const float* __restrict__ in3,
                                            __hip_bfloat16* __restrict__ o1,
                                            __hip_bfloat16* __restrict__ o2,
                                            __hip_bfloat16* __restrict__ o3) {
  int i = blockIdx.x * 256 + threadIdx.x;
  const float* in;
  __hip_bfloat16* out;
  if (i < CVT_N1) { in = in1; out = o1; }
  else if (i < CVT_N1 + CVT_N2) { in = in2; out = o2; i -= CVT_N1; }
  else { in = in3; out = o3; i -= CVT_N1 + CVT_N2; }
  const float4 v = ((const float4*)in)[i];
  __hip_bfloat162 p0, p1;
  p0.x = __float2bfloat16(v.x); p0.y = __float2bfloat16(v.y);
  p1.x = __float2bfloat16(v.z); p1.y = __float2bfloat16(v.w);
  __hip_bfloat162* o = (__hip_bfloat162*)(out + (size_t)i * 4);
  o[0] = p0; o[1] = p1;
}

// ------- gemm1: 128x128, BK=32, reg-staged dbuf, 32KB LDS, all-resident ------
// LDS chunk (row, p) at (row*4 + p)*8 shorts; position p holds global k-chunk
// p ^ (row&3) ^ ((row>>2)&1)  (equivalently: global chunk c stored at
// c ^ (row&3) ^ ((row>>2)&1); the swizzle is an involution).
__global__ __launch_bounds__(256) void gemm1_c(const __hip_bfloat16* __restrict__ A,
                                               const __hip_bfloat16* __restrict__ B,
                                               const float* __restrict__ bias,
                                               __hip_bfloat16* __restrict__ C,
                                               int M, int N, int K) {
  __shared__ __align__(16) short Abuf[2][4096];  // 8 KB each
  __shared__ __align__(16) short Bbuf[2][4096];  // 8 KB each -> 32 KB total
  const int tid  = threadIdx.x;
  const int wave = tid >> 6;
  const int lane = tid & 63;
  const int quad = lane >> 4;
  const int l16  = lane & 15;
  const int bm = blockIdx.x * 128;   // M fastest: consecutive blocks share B
  const int bn = blockIdx.y * 128;
  const int wm = (wave >> 1) * 64;
  const int wn = (wave & 1) * 64;

  const int srow = tid >> 2;         // 0..63
  const int skh  = tid & 3;          // global k-chunk this thread fetches
  const __hip_bfloat16* Ag[2];
  const __hip_bfloat16* Bg[2];
  int So[2];
  #pragma unroll
  for (int l = 0; l < 2; ++l) {
    const int row = l * 64 + srow;
    Ag[l] = A + (size_t)(bm + row) * K + skh * 8;
    Bg[l] = B + (size_t)(bn + row) * K + skh * 8;
    So[l] = (row * 4 + (skh ^ (row & 3) ^ ((row >> 2) & 1))) * 8;
  }

  v4f acc[4][4];
  const v4f vz = {0.f, 0.f, 0.f, 0.f};
  #pragma unroll
  for (int i = 0; i < 4; ++i)
    #pragma unroll
    for (int j = 0; j < 4; ++j) acc[i][j] = vz;

  // read-side swizzle: chunk quad of row r is at quad ^ (r&3) ^ ((r>>2)&1);
  // r = wm + i*16 + l16 -> r&3 == l16&3, (r>>2)&1 == (l16>>2)&1.
  const int khx = quad ^ (l16 & 3) ^ ((l16 >> 2) & 1);
  const int nk = K >> 5;             // 40 slabs of 32
  v8s ra[2], rb[2];

  #pragma unroll
  for (int l = 0; l < 2; ++l) { ra[l] = *(const v8s*)Ag[l]; rb[l] = *(const v8s*)Bg[l]; }
  #pragma unroll
  for (int l = 0; l < 2; ++l) {
    *(v8s*)&Abuf[0][So[l]] = ra[l];
    *(v8s*)&Bbuf[0][So[l]] = rb[l];
  }
  __syncthreads();

  for (int k = 0; k < nk; ++k) {
    const int cur = k & 1;
    const bool more = (k + 1 < nk);
    if (more) {
      const int off = (k + 1) * 32;
      #pragma unroll
      for (int l = 0; l < 2; ++l) {
        ra[l] = *(const v8s*)(Ag[l] + off);
        rb[l] = *(const v8s*)(Bg[l] + off);
      }
    }
    v8s af[4], bf[4];
    #pragma unroll
    for (int i = 0; i < 4; ++i) {
      af[i] = *(const v8s*)&Abuf[cur][((wm + i * 16 + l16) * 4 + khx) * 8];
      bf[i] = *(const v8s*)&Bbuf[cur][((wn + i * 16 + l16) * 4 + khx) * 8];
    }
    #pragma unroll
    for (int i = 0; i < 4; ++i)
      #pragma unroll
      for (int j = 0; j < 4; ++j)
        acc[i][j] = __builtin_amdgcn_mfma_f32_16x16x32_bf16(af[i], bf[j], acc[i][j], 0, 0, 0);
    if (more) {
      #pragma unroll
      for (int l = 0; l < 2; ++l) {
        *(v8s*)&Abuf[1 - cur][So[l]] = ra[l];
        *(v8s*)&Bbuf[1 - cur][So[l]] = rb[l];
      }
    }
    __syncthreads();
  }

  #pragma unroll
  for (int j = 0; j < 4; ++j) {
    const int col = bn + wn + j * 16 + l16;
    const float bj = bias[col];
    #pragma unroll
    for (int i = 0; i < 4; ++i) {
      const int row0 = bm + wm + i * 16 + quad * 4;
      #pragma unroll
      for (int r = 0; r < 4; ++r)
        C[(size_t)(row0 + r) * N + col] = __float2bfloat16(acc[i][j][r] + bj);
    }
  }
}

// ---------------- gemm2: 64x128, BK=64, r15 reg-staged + XOR swizzle ----------
__global__ __launch_bounds__(256) void gemm2_c(const __hip_bfloat16* __restrict__ A,
                                               const __hip_bfloat16* __restrict__ B,
                                               const float* __restrict__ bias,
                                               float* __restrict__ C,
                                               int M, int N, int K) {
  __shared__ __align__(16) short Abuf[2][4096];  // 8 KB each
  __shared__ __align__(16) short Bbuf[2][8192];  // 16 KB each
  const int tid  = threadIdx.x;
  const int wave = tid >> 6;
  const int lane = tid & 63;
  const int quad = lane >> 4;
  const int l16  = lane & 15;
  const int bm = blockIdx.x * 64;    // M fastest
  const int bn = blockIdx.y * 128;
  const int wm = (wave & 1) * 32;
  const int wn = (wave >> 1) * 64;

  const int srow = tid >> 3;
  const int skh  = tid & 7;
  const __hip_bfloat16* Ag[2];
  const __hip_bfloat16* Bg[4];
  int Ao[2], Bo[4];
  #pragma unroll
  for (int l = 0; l < 2; ++l) {
    const int row = l * 32 + srow;
    Ag[l] = A + (size_t)(bm + row) * K + skh * 8;
    Ao[l] = (row * 8 + (skh ^ (row & 7))) * 8;
  }
  #pragma unroll
  for (int l = 0; l < 4; ++l) {
    const int row = l * 32 + srow;
    Bg[l] = B + (size_t)(bn + row) * K + skh * 8;
    Bo[l] = (row * 8 + (skh ^ (row & 7))) * 8;
  }

  v4f acc[2][4];
  const v4f vz = {0.f, 0.f, 0.f, 0.f};
  #pragma unroll
  for (int i = 0; i < 2; ++i)
    #pragma unroll
    for (int j = 0; j < 4; ++j) acc[i][j] = vz;

  const int sw = l16 & 7;
  const int nk = K >> 6;
  v8s ra[2], rb[4];

  #pragma unroll
  for (int l = 0; l < 2; ++l) ra[l] = *(const v8s*)Ag[l];
  #pragma unroll
  for (int l = 0; l < 4; ++l) rb[l] = *(const v8s*)Bg[l];
  #pragma unroll
  for (int l = 0; l < 2; ++l) *(v8s*)&Abuf[0][Ao[l]] = ra[l];
  #pragma unroll
  for (int l = 0; l < 4; ++l) *(v8s*)&Bbuf[0][Bo[l]] = rb[l];
  __syncthreads();

  for (int k = 0; k < nk; ++k) {
    const int cur = k & 1;
    const bool more = (k + 1 < nk);
    if (more) {
      const int off = (k + 1) * 64;
      #pragma unroll
      for (int l = 0; l < 2; ++l) ra[l] = *(const v8s*)(Ag[l] + off);
      #pragma unroll
      for (int l = 0; l < 4; ++l) rb[l] = *(const v8s*)(Bg[l] + off);
    }
    #pragma unroll
    for (int s = 0; s < 2; ++s) {
      const int khx = (s * 4 + quad) ^ sw;
      v8s af[2], bf[4];
      #pragma unroll
      for (int i = 0; i < 2; ++i)
        af[i] = *(const v8s*)&Abuf[cur][((wm + i * 16 + l16) * 8 + khx) * 8];
      #pragma unroll
      for (int j = 0; j < 4; ++j)
        bf[j] = *(const v8s*)&Bbuf[cur][((wn + j * 16 + l16) * 8 + khx) * 8];
      #pragma unroll
      for (int i = 0; i < 2; ++i)
        #pragma unroll
        for (int j = 0; j < 4; ++j)
          acc[i][j] = __builtin_amdgcn_mfma_f32_16x16x32_bf16(af[i], bf[j], acc[i][j], 0, 0, 0);
    }
    if (more) {
      #pragma unroll
      for (int l = 0; l < 2; ++l) *(v8s*)&Abuf[1 - cur][Ao[l]] = ra[l];
      #pragma unroll
      for (int l = 0; l < 4; ++l) *(v8s*)&Bbuf[1 - cur][Bo[l]] = rb[l];
    }
    __syncthreads();
  }

  #pragma unroll
  for (int j = 0; j < 4; ++j) {
    const int col = bn + wn + j * 16 + l16;
    const float bj = bias[col];
    #pragma unroll
    for (int i = 0; i < 2; ++i) {
      const int row0 = bm + wm + i * 16 + quad * 4;
      #pragma unroll
      for (int r = 0; r < 4; ++r)
        C[(size_t)(row0 + r) * N + col] = acc[i][j][r] + bj;
    }
  }
}

// ---------------- merged pack kernel (unchanged) ----------------
#define QK_BLOCKS ((2 * S_TOT * 16 * 12) / 256)   // 4608
#define V_BLOCKS  ((3 * 16 * 16 * 8 * 96) / 256)  // 2304
__global__ __launch_bounds__(256) void pack_all(const __hip_bfloat16* __restrict__ qkv,
                                                const float* __restrict__ cos_,
                                                const float* __restrict__ sin_,
                                                short* __restrict__ Qp,
                                                short* __restrict__ Kp,
                                                short* __restrict__ Vp) {
  const int bid = blockIdx.x;
  if (bid < QK_BLOCKS) {
    const int idx = bid * 256 + threadIdx.x;
    const int kd = idx % 12;
    const int h  = (idx / 12) % 16;
    const int s  = (idx / 192) % S_TOT;
    const int p  = idx / (192 * S_TOT);
    const int seg = s >> 10, tb = (s >> 6) & 15, t = s & 63;
    short* out = (p ? Kp : Qp) +
                 ((size_t)(((seg * 16 + h) * 16 + tb) * 12 + kd) * 64 + t) * 8;
    short tmp[8];
    if (kd >= 10) {
      #pragma unroll
      for (int j = 0; j < 8; ++j) tmp[j] = 0;
      *(int4*)out = *(int4*)tmp;
      return;
    }
    const short* row = (const short*)qkv + (size_t)s * TDIM + p * DIM + h * HD;
    const int d0 = kd * 8;
    const v8s xm = *(const v8s*)(row + d0);
    const v8s xr = *(const v8s*)(row + d0 + ((kd < 5) ? 40 : -40));
    const float sgn = (kd < 5) ? -1.f : 1.f;
    const float scale = (p == 0) ? 0.111803398874989485f : 1.0f;
    #pragma unroll
    for (int j = 0; j < 8; ++j) {
      const int d = d0 + j;
      const float v = (bf2f(xm[j]) * cos_[s * HD + d] +
                       sgn * bf2f(xr[j]) * sin_[s * HD + d]) * scale;
      tmp[j] = f2bf(v);
    }
    *(int4*)out = *(int4*)tmp;
  } else {
    const int idx = (bid - QK_BLOCKS) * 256 + threadIdx.x;
    const int d  = idx % 96;
    const int td = (idx / 96) % 8;
    const int tb = (idx / 768) % 16;
    const int h  = (idx / (768 * 16)) % 16;
    const int seg = idx / (768 * 256);
    const int s0 = seg * SEG + tb * 64 + td * 8;
    const short* q = (const short*)qkv;
    short tmp[8];
    if (d < 80) {
      #pragma unroll
      for (int j = 0; j < 8; ++j)
        tmp[j] = q[(size_t)(s0 + j) * TDIM + 2 * DIM + h * HD + d];
    } else {
      const short fill = (d == 80) ? (short)0x3F80 : (short)0;
      #pragma unroll
      for (int j = 0; j < 8; ++j) tmp[j] = fill;
    }
    *(int4*)(Vp + (size_t)idx * 8) = *(int4*)tmp;
  }
}

// -------- fused flash MFMA attention (r19 XCD group mapping, kept) ----------
// 1D grid 768. xcd = l%8 owns 6 complete (seg,h) groups; all 16 qt-blocks of a
// group land on the same XCD -> its 384KB K/V panel is L2-resident and reused.
__global__ __launch_bounds__(256, 4) void attn_mfma(const short* __restrict__ Qp,
                                                    const short* __restrict__ Kp,
                                                    const short* __restrict__ Vp,
                                                    __hip_bfloat16* __restrict__ out) {
  __shared__ __align__(16) short Ks[64 * 96];
  __shared__ __align__(16) short Vs[64 * 96];
  __shared__ __align__(16) short Ps[4][16 * 68];

  const int l   = blockIdx.x;
  const int xcd = l & 7;
  const int j8  = l >> 3;            // 0..95
  const int g   = xcd * 6 + (j8 >> 4);  // group 0..47  (= seg*16 + h)
  const int qt  = j8 & 15;
  const int h   = g & 15;
  const int seg = g >> 4;
  const int tid  = threadIdx.x;
  const int wave = tid >> 6;
  const int lane = tid & 63;
  const int quad = lane >> 4;
  const int l16  = lane & 15;
  const int sh16 = g;

  const short* Qg = Qp + (size_t)(sh16 * 16 + qt) * 6144;
  const short* Kg = Kp + (size_t)sh16 * 16 * 6144;
  const short* Vg = Vp + (size_t)sh16 * 16 * 6144;

  v8s af[3];
  #pragma unroll
  for (int ks = 0; ks < 3; ++ks)
    af[ks] = *(const v8s*)(Qg + ((ks * 4 + quad) * 64 + wave * 16 + l16) * 8);

  v8s kr[3], vr[3];
  #pragma unroll
  for (int it = 0; it < 3; ++it) {
    const int o = (it * 256 + tid) * 8;
    kr[it] = *(const v8s*)(Kg + o);
    vr[it] = *(const v8s*)(Vg + o);
  }
  #pragma unroll
  for (int it = 0; it < 3; ++it) {
    const int o = (it * 256 + tid) * 8;
    *(v8s*)&Ks[o] = kr[it];
    *(v8s*)&Vs[o] = vr[it];
  }
  __syncthreads();

  v4f o4[6];
  const v4f vz = {0.f, 0.f, 0.f, 0.f};
  #pragma unroll
  for (int n = 0; n < 6; ++n) o4[n] = vz;

  for (int kb = 0; kb < 16; ++kb) {
    const bool more = (kb + 1 < 16);
    if (more) {
      const size_t base = (size_t)(kb + 1) * 6144;
      #pragma unroll
      for (int it = 0; it < 3; ++it) {
        const int o = (it * 256 + tid) * 8;
        kr[it] = *(const v8s*)(Kg + base + o);
        vr[it] = *(const v8s*)(Vg + base + o);
      }
    }

    v4f s4[4];
    #pragma unroll
    for (int j = 0; j < 4; ++j) {
      s4[j] = vz;
      #pragma unroll
      for (int ks = 0; ks < 3; ++ks) {
        const v8s bf = *(const v8s*)&Ks[((ks * 4 + quad) * 64 + j * 16 + l16) * 8];
        s4[j] = __builtin_amdgcn_mfma_f32_16x16x32_bf16(af[ks], bf, s4[j], 0, 0, 0);
      }
    }

    #pragma unroll
    for (int reg = 0; reg < 4; ++reg)
      #pragma unroll
      for (int j = 0; j < 4; ++j)
        Ps[wave][(quad * 4 + reg) * 68 + j * 16 + l16] = f2bf(__expf(s4[j][reg]));

    v8s pa[2];
    #pragma unroll
    for (int kp = 0; kp < 2; ++kp)
      pa[kp] = *(const v8s*)&Ps[wave][l16 * 68 + kp * 32 + quad * 8];
    #pragma unroll
    for (int n = 0; n < 6; ++n) {
      #pragma unroll
      for (int kp = 0; kp < 2; ++kp) {
        const v8s vb = *(const v8s*)&Vs[((kp * 4 + quad) * 96 + n * 16 + l16) * 8];
        o4[n] = __builtin_amdgcn_mfma_f32_16x16x32_bf16(pa[kp], vb, o4[n], 0, 0, 0);
      }
    }

    __syncthreads();
    if (more) {
      #pragma unroll
      for (int it = 0; it < 3; ++it) {
        const int o = (it * 256 + tid) * 8;
        *(v8s*)&Ks[o] = kr[it];
        *(v8s*)&Vs[o] = vr[it];
      }
    }
    __syncthreads();
  }

  float inv[4];
  #pragma unroll
  for (int r = 0; r < 4; ++r)
    inv[r] = 1.f / __shfl(o4[5][r], quad << 4);
  const int row0 = seg * SEG + qt * 64 + wave * 16 + quad * 4;
  #pragma unroll
  for (int n = 0; n < 5; ++n) {
    const int col = h * HD + n * 16 + l16;
    #pragma unroll
    for (int r = 0; r < 4; ++r)
      out[(size_t)(row0 + r) * DIM + col] = __float2bfloat16(o4[n][r] * inv[r]);
  }
}

extern "C" void kernel_launch(void* const* d_in, const int* in_sizes, int n_in,
                              void* d_out, int out_size, void* d_ws, size_t ws_size,
                              hipStream_t stream) {
  (void)in_sizes; (void)n_in; (void)out_size; (void)ws_size;
  const float* hs     = (const float*)d_in[0];
  const float* cosp   = (const float*)d_in[1];
  const float* sinp   = (const float*)d_in[2];
  const float* qkv_w  = (const float*)d_in[3];
  const float* qkv_b  = (const float*)d_in[4];
  const float* proj_w = (const float*)d_in[5];
  const float* proj_b = (const float*)d_in[6];

  float* out_f = (float*)d_out;
  __hip_bfloat16* qkv_b16 = (__hip_bfloat16*)d_ws;                     // [A]
  __hip_bfloat16* hs_b    = qkv_b16 + (size_t)S_TOT * TDIM;            // [B]
  __hip_bfloat16* qkvw_b  = hs_b + (size_t)S_TOT * DIM;                // [C]
  __hip_bfloat16* projw_b = qkvw_b + (size_t)TDIM * DIM;               // [D]
  short* Qp = (short*)qkvw_b;                                          // alias [C]
  short* Kp = (short*)(projw_b + (size_t)DIM * DIM);                   // [E]
  short* Vp = Kp + (size_t)3 * 16 * 16 * 6144;                         // [F]
  __hip_bfloat16* attn_b = hs_b;                                       // alias [B]

  cvt3<<<(CVT_N1 + CVT_N2 + CVT_N3) / 256, 256, 0, stream>>>(
      hs, qkv_w, proj_w, hs_b, qkvw_b, projw_b);

  gemm1_c<<<dim3(S_TOT / 128, TDIM / 128), 256, 0, stream>>>(
      hs_b, qkvw_b, qkv_b, qkv_b16, S_TOT, TDIM, DIM);

  pack_all<<<QK_BLOCKS + V_BLOCKS, 256, 0, stream>>>(qkv_b16, cosp, sinp, Qp, Kp, Vp);

  attn_mfma<<<dim3(768), 256, 0, stream>>>(Qp, Kp, Vp, attn_b);

  gemm2_c<<<dim3(S_TOT / 64, DIM / 128), 256, 0, stream>>>(
      attn_b, projw_b, proj_b, out_f, S_TOT, DIM, DIM);
}